// Round 9
// baseline (178.370 us; speedup 1.0000x reference)
//
#include <hip/hip_runtime.h>
#include <math.h>

#define D_PET 128
#define NK    256
#define NB    2048
#define NBATCH 16

__device__ __forceinline__ float silu(float x) {
    return x / (1.0f + expf(-x));
}

__device__ __forceinline__ int lower_bound_dev(const int* a, int n, int v) {
    int lo = 0, hi = n;
    while (lo < hi) {
        int m = (lo + hi) >> 1;
        if (a[m] < v) lo = m + 1; else hi = m;
    }
    return lo;
}

// ---------------------------------------------------------------------------
// Kernel A (fused): blocks [0,512) = s-partial blocks (b, 16-k tile, 2-way
// atom split; on-the-fly phases in LDS; one h float4 -> 16 FMA), blocks
// [512,1024) = MLP -> filt.
// ---------------------------------------------------------------------------
#define S_BLOCKS 512
#define MJ 8

// 4-atom sub-chunk: 4 h float4 loads + 8 LDS float2 -> 64 FMA
#define SLOAD(S, c0)                                                         \
    do {                                                                     \
        _Pragma("unroll")                                                    \
        for (int i_ = 0; i_ < 4; i_++) {                                     \
            int a_ = (c0) * 4 + i_;                                          \
            hb##S[i_]  = *(const float4*)(hp + (size_t)(base + a_) * D_PET); \
            cb0##S[i_] = csl[a_ * 16 + kq2];                                 \
            cb1##S[i_] = csl[a_ * 16 + kq2 + 1];                             \
        }                                                                    \
    } while (0)

#define SFMA(S)                                                              \
    do {                                                                     \
        _Pragma("unroll")                                                    \
        for (int i_ = 0; i_ < 4; i_++) {                                     \
            float4 hv = hb##S[i_];                                           \
            float2 c0 = cb0##S[i_], c1 = cb1##S[i_];                         \
            re0[0]=fmaf(c0.x,hv.x,re0[0]); im0[0]=fmaf(-c0.y,hv.x,im0[0]);   \
            re0[1]=fmaf(c0.x,hv.y,re0[1]); im0[1]=fmaf(-c0.y,hv.y,im0[1]);   \
            re0[2]=fmaf(c0.x,hv.z,re0[2]); im0[2]=fmaf(-c0.y,hv.z,im0[2]);   \
            re0[3]=fmaf(c0.x,hv.w,re0[3]); im0[3]=fmaf(-c0.y,hv.w,im0[3]);   \
            re1[0]=fmaf(c1.x,hv.x,re1[0]); im1[0]=fmaf(-c1.y,hv.x,im1[0]);   \
            re1[1]=fmaf(c1.x,hv.y,re1[1]); im1[1]=fmaf(-c1.y,hv.y,im1[1]);   \
            re1[2]=fmaf(c1.x,hv.z,re1[2]); im1[2]=fmaf(-c1.y,hv.z,im1[2]);   \
            re1[3]=fmaf(c1.x,hv.w,re1[3]); im1[3]=fmaf(-c1.y,hv.w,im1[3]);   \
        }                                                                    \
    } while (0)

__global__ void __launch_bounds__(256) smlp_kernel(
                           const float* __restrict__ kvec,
                           const float* __restrict__ pos,
                           const float* __restrict__ h,
                           const int* __restrict__ batch,
                           const float* __restrict__ W1, const float* __restrict__ b1,
                           const float* __restrict__ W2, const float* __restrict__ b2,
                           const float* __restrict__ W3, const float* __restrict__ b3,
                           float* __restrict__ filt,
                           float* __restrict__ ts0,
                           float* __restrict__ ts1) {
    __shared__ float smem[48 + 4096];   // s: kv[16][3] + cs[64][16] f2 ; mlp: kv + x_lds

    if (blockIdx.x < S_BLOCKS) {
        // ---- s-partial: block = (b, kt of 16 k, sp atom half) ----
        int bi = blockIdx.x;
        int v  = (bi & 7) * 64 + (bi >> 3);   // XCD-contiguous, bijective (512)
        int b  = v >> 5;
        int r  = v & 31;
        int kt = r >> 1;
        int sp = r & 1;
        int dq = threadIdx.x & 31;
        int kq = threadIdx.x >> 5;            // 0..7
        int kq2 = kq * 2;                     // thread k's: kt*16 + kq2 + {0,1}
        int d0 = dq * 4;

        float*  kv_s = smem;                  // [16][3]
        float2* csl  = (float2*)(smem + 48);  // [64][16]

        if (threadIdx.x < 48)
            kv_s[threadIdx.x] = kvec[((size_t)b * NK + kt * 16) * 3 + threadIdx.x];

        int lo = lower_bound_dev(batch, NB, b);
        int hi = lower_bound_dev(batch, NB, b + 1);
        int cnt = hi - lo;
        int a0 = lo + ((cnt * sp) >> 1);
        int a1 = lo + ((cnt * (sp + 1)) >> 1);

        float re0[4] = {0.f,0.f,0.f,0.f}, im0[4] = {0.f,0.f,0.f,0.f};
        float re1[4] = {0.f,0.f,0.f,0.f}, im1[4] = {0.f,0.f,0.f,0.f};
        const float* hp = h + d0;

        for (int base = a0; base < a1; base += 64) {
            int m = a1 - base; if (m > 64) m = 64;
            __syncthreads();   // kv_s ready (1st iter) / prev chunk reads done
            // stage phases: thread -> atom (tid>>2), 4 k's ((tid&3)*4 + i)
            {
                int a = threadIdx.x >> 2;
                if (a < m) {
                    int n = base + a;
                    float p0 = pos[n*3+0], p1 = pos[n*3+1], p2 = pos[n*3+2];
                    int kk0 = (threadIdx.x & 3) * 4;
#pragma unroll
                    for (int i = 0; i < 4; i++) {
                        int kk = kk0 + i;
                        float ph = p0*kv_s[kk*3+0] + p1*kv_s[kk*3+1] + p2*kv_s[kk*3+2];
                        float sv, cv; sincosf(ph, &sv, &cv);
                        csl[a * 16 + kk] = make_float2(cv, sv);
                    }
                }
            }
            __syncthreads();

            float4 hbA[4], hbB[4];
            float2 cb0A[4], cb1A[4], cb0B[4], cb1B[4];
            int nch = m >> 2;
            if (nch) {
                SLOAD(A, 0);
                int c = 1;
                for (; c + 1 < nch; c += 2) {
                    SLOAD(B, c);     __builtin_amdgcn_sched_barrier(0); SFMA(A);
                    SLOAD(A, c + 1); __builtin_amdgcn_sched_barrier(0); SFMA(B);
                }
                if (c < nch) {
                    SLOAD(B, c); __builtin_amdgcn_sched_barrier(0);
                    SFMA(A); SFMA(B);
                } else {
                    __builtin_amdgcn_sched_barrier(0); SFMA(A);
                }
            }
            for (int a = nch * 4; a < m; a++) {
                float4 hv = *(const float4*)(hp + (size_t)(base + a) * D_PET);
                float2 c0 = csl[a * 16 + kq2];
                float2 c1 = csl[a * 16 + kq2 + 1];
                re0[0]=fmaf(c0.x,hv.x,re0[0]); im0[0]=fmaf(-c0.y,hv.x,im0[0]);
                re0[1]=fmaf(c0.x,hv.y,re0[1]); im0[1]=fmaf(-c0.y,hv.y,im0[1]);
                re0[2]=fmaf(c0.x,hv.z,re0[2]); im0[2]=fmaf(-c0.y,hv.z,im0[2]);
                re0[3]=fmaf(c0.x,hv.w,re0[3]); im0[3]=fmaf(-c0.y,hv.w,im0[3]);
                re1[0]=fmaf(c1.x,hv.x,re1[0]); im1[0]=fmaf(-c1.y,hv.x,im1[0]);
                re1[1]=fmaf(c1.x,hv.y,re1[1]); im1[1]=fmaf(-c1.y,hv.y,im1[1]);
                re1[2]=fmaf(c1.x,hv.z,re1[2]); im1[2]=fmaf(-c1.y,hv.z,im1[2]);
                re1[3]=fmaf(c1.x,hv.w,re1[3]); im1[3]=fmaf(-c1.y,hv.w,im1[3]);
            }
        }

        int k0 = kt * 16 + kq2;
        float* dst = sp ? ts1 : ts0;
        size_t o = (((size_t)b * NK + k0) * D_PET + d0) * 2;
        *(float4*)(dst + o)       = make_float4(re0[0], im0[0], re0[1], im0[1]);
        *(float4*)(dst + o + 4)   = make_float4(re0[2], im0[2], re0[3], im0[3]);
        *(float4*)(dst + o + 256) = make_float4(re1[0], im1[0], re1[1], im1[1]);
        *(float4*)(dst + o + 260) = make_float4(re1[2], im1[2], re1[3], im1[3]);
        return;
    }

    // ---- MLP: filt[b,k,:] ----
    int bk0 = (blockIdx.x - S_BLOCKS) * MJ;
    int d   = threadIdx.x & (D_PET - 1);
    int jg  = threadIdx.x >> 7;

    float* kv_s  = smem;          // [MJ*3]
    float* x_lds = smem + 48;     // [D_PET*MJ]

    if (threadIdx.x < MJ * 3) kv_s[threadIdx.x] = kvec[bk0 * 3 + threadIdx.x];
    __syncthreads();

    float w10 = W1[0 * D_PET + d], w11 = W1[1 * D_PET + d], w12 = W1[2 * D_PET + d];
    float bb1 = b1[d];
    float4 x1;
    {
        float* xp = (float*)&x1;
#pragma unroll
        for (int i = 0; i < 4; i++) {
            int j = jg * 4 + i;
            float a = bb1;
            a = fmaf(kv_s[j * 3 + 0], w10, a);
            a = fmaf(kv_s[j * 3 + 1], w11, a);
            a = fmaf(kv_s[j * 3 + 2], w12, a);
            xp[i] = silu(a);
        }
    }
    *(float4*)&x_lds[(d << 3) + (jg << 2)] = x1;
    __syncthreads();

    float acc0 = b2[d], acc1 = acc0, acc2 = acc0, acc3 = acc0;
#pragma unroll
    for (int e0 = 0; e0 < D_PET; e0 += 8) {
        float w[8];
#pragma unroll
        for (int i = 0; i < 8; i++) w[i] = W2[(e0 + i) * D_PET + d];
        __builtin_amdgcn_sched_barrier(0);
#pragma unroll
        for (int i = 0; i < 8; i++) {
            float4 xv = *(const float4*)&x_lds[((e0 + i) << 3) + (jg << 2)];
            acc0 = fmaf(xv.x, w[i], acc0);
            acc1 = fmaf(xv.y, w[i], acc1);
            acc2 = fmaf(xv.z, w[i], acc2);
            acc3 = fmaf(xv.w, w[i], acc3);
        }
    }
    float4 x2 = make_float4(silu(acc0), silu(acc1), silu(acc2), silu(acc3));
    __syncthreads();
    *(float4*)&x_lds[(d << 3) + (jg << 2)] = x2;
    __syncthreads();

    float o0 = b3[d], o1 = o0, o2 = o0, o3 = o0;
#pragma unroll
    for (int e0 = 0; e0 < D_PET; e0 += 8) {
        float w[8];
#pragma unroll
        for (int i = 0; i < 8; i++) w[i] = W3[(e0 + i) * D_PET + d];
        __builtin_amdgcn_sched_barrier(0);
#pragma unroll
        for (int i = 0; i < 8; i++) {
            float4 xv = *(const float4*)&x_lds[((e0 + i) << 3) + (jg << 2)];
            o0 = fmaf(xv.x, w[i], o0);
            o1 = fmaf(xv.y, w[i], o1);
            o2 = fmaf(xv.z, w[i], o2);
            o3 = fmaf(xv.w, w[i], o3);
        }
    }
    float out4[4] = {o0, o1, o2, o3};
#pragma unroll
    for (int i = 0; i < 4; i++) {
        int j = jg * 4 + i;
        filt[(size_t)(bk0 + j) * D_PET + d] = out4[i];
    }
}

// ---------------------------------------------------------------------------
// Kernel B (v9): out[n,d] = sum_k e^{+i phi_nk} * (ts0+ts1)[b,k,d]*filt[b,k,d]
// grid = 256 blocks x 512 threads. Block = 8 atoms x 128 d; thread =
// (d-pair dg, k-eighth w, ALL 8 atoms). t0/t1/filt loaded ONCE per block;
// per k: 3 global loads -> 64 FMA (8 atoms x 2 d x 4). Phases in LDS.
// 3-set rotated pipeline. Staged 8-way LDS reduce over k-eighths.
// ---------------------------------------------------------------------------
#define OLOAD(S, cc)                                                         \
    do {                                                                     \
        int k_ = k0 + (cc);                                                  \
        t0_##S = *(const float4*)(tb0 + (size_t)k_ * 256);                   \
        t1_##S = *(const float4*)(tb1 + (size_t)k_ * 256);                   \
        f_##S  = *(const float2*)(fb  + (size_t)k_ * 128);                   \
    } while (0)

#define OFMA(S, cc)                                                          \
    do {                                                                     \
        int k_ = k0 + (cc);                                                  \
        float tr0 = (t0_##S.x + t1_##S.x) * f_##S.x;                         \
        float ti0 = (t0_##S.y + t1_##S.y) * f_##S.x;                         \
        float tr1 = (t0_##S.z + t1_##S.z) * f_##S.y;                         \
        float ti1 = (t0_##S.w + t1_##S.w) * f_##S.y;                         \
        _Pragma("unroll")                                                    \
        for (int a_ = 0; a_ < 8; a_++) {                                     \
            float2 q = cs[a_ * 256 + k_];                                    \
            acc[a_].x = fmaf(q.x,tr0,acc[a_].x); acc[a_].x = fmaf(-q.y,ti0,acc[a_].x); \
            acc[a_].y = fmaf(q.x,ti0,acc[a_].y); acc[a_].y = fmaf( q.y,tr0,acc[a_].y); \
            acc[a_].z = fmaf(q.x,tr1,acc[a_].z); acc[a_].z = fmaf(-q.y,ti1,acc[a_].z); \
            acc[a_].w = fmaf(q.x,ti1,acc[a_].w); acc[a_].w = fmaf( q.y,tr1,acc[a_].w); \
        }                                                                    \
    } while (0)

__global__ void __launch_bounds__(512) out_kernel(
                           const float* __restrict__ kvec,
                           const float* __restrict__ pos,
                           const int* __restrict__ batch,
                           const float* __restrict__ ts0,
                           const float* __restrict__ ts1,
                           const float* __restrict__ filt,
                           float* __restrict__ out, int interleaved) {
    __shared__ float2 cs[8 * 256];          // 16 KB phases
    __shared__ float4 red4[4][64][8];       // 32 KB staged reduce

    int bi = blockIdx.x;
    int v  = (bi & 7) * 32 + (bi >> 3);     // XCD-contiguous, bijective (256)
    int nb = v * 8;
    int dg = threadIdx.x & 63;
    int w  = threadIdx.x >> 6;              // 0..7 -> k-eighth
    int d0 = dg * 2;
    int k0 = w * 32;

    // stage phases: 4 (atom,k) pairs per thread (consecutive k, same atom)
#pragma unroll
    for (int i = 0; i < 4; i++) {
        int p = threadIdx.x * 4 + i;
        int a = p >> 8, k = p & 255;
        int n = nb + a;
        int b = batch[n];
        const float* kv = kvec + ((size_t)b * NK + k) * 3;
        float ph = pos[n*3+0]*kv[0] + pos[n*3+1]*kv[1] + pos[n*3+2]*kv[2];
        float sv, cv; sincosf(ph, &sv, &cv);
        cs[a * 256 + k] = make_float2(cv, sv);
    }
    __syncthreads();

    float4 acc[8];
#pragma unroll
    for (int a = 0; a < 8; a++) acc[a] = make_float4(0.f, 0.f, 0.f, 0.f);

    int bq = batch[nb];
    bool uni = (bq == batch[nb + 7]);       // sorted => block uniform

    if (uni) {
        const float* tb0 = ts0  + ((size_t)bq * NK * D_PET + d0) * 2;
        const float* tb1 = ts1  + ((size_t)bq * NK * D_PET + d0) * 2;
        const float* fb  = filt +  (size_t)bq * NK * D_PET + d0;

        float4 t0_0, t0_1, t0_2, t1_0, t1_1, t1_2;
        float2 f_0, f_1, f_2;

        OLOAD(0, 0); OLOAD(1, 1);
        for (int c = 0; c < 30; c += 3) {
            OLOAD(2, c + 2); __builtin_amdgcn_sched_barrier(0); OFMA(0, c);
            OLOAD(0, c + 3); __builtin_amdgcn_sched_barrier(0); OFMA(1, c + 1);
            OLOAD(1, c + 4); __builtin_amdgcn_sched_barrier(0); OFMA(2, c + 2);
        }
        // chunks 30 (set 0), 31 (set 1) already loaded
        __builtin_amdgcn_sched_barrier(0);
        OFMA(0, 30); OFMA(1, 31);
    } else {
        // batch boundary inside the 8 atoms (rare): per-atom streams
#pragma unroll
        for (int a = 0; a < 8; a++) {
            int n = nb + a;
            int b = batch[n];
            const float* tb0 = ts0  + ((size_t)b * NK * D_PET + d0) * 2;
            const float* tb1 = ts1  + ((size_t)b * NK * D_PET + d0) * 2;
            const float* fb  = filt +  (size_t)b * NK * D_PET + d0;
            for (int k = k0; k < k0 + 32; k++) {
                float4 u0 = *(const float4*)(tb0 + (size_t)k * 256);
                float4 u1 = *(const float4*)(tb1 + (size_t)k * 256);
                float2 f  = *(const float2*)(fb  + (size_t)k * 128);
                float2 q  = cs[a * 256 + k];
                float tr0 = (u0.x + u1.x) * f.x, ti0 = (u0.y + u1.y) * f.x;
                float tr1 = (u0.z + u1.z) * f.y, ti1 = (u0.w + u1.w) * f.y;
                acc[a].x = fmaf(q.x,tr0,acc[a].x); acc[a].x = fmaf(-q.y,ti0,acc[a].x);
                acc[a].y = fmaf(q.x,ti0,acc[a].y); acc[a].y = fmaf( q.y,tr0,acc[a].y);
                acc[a].z = fmaf(q.x,tr1,acc[a].z); acc[a].z = fmaf(-q.y,ti1,acc[a].z);
                acc[a].w = fmaf(q.x,ti1,acc[a].w); acc[a].w = fmaf( q.y,tr1,acc[a].w);
            }
        }
    }

    // staged 8-way reduce over k-eighths (reuse red4, WAR-safe barriers)
    if (w >= 4) {
#pragma unroll
        for (int a = 0; a < 8; a++) red4[w - 4][dg][a] = acc[a];
    }
    __syncthreads();
    if (w < 4) {
#pragma unroll
        for (int a = 0; a < 8; a++) {
            float4 r = red4[w][dg][a];
            acc[a].x += r.x; acc[a].y += r.y; acc[a].z += r.z; acc[a].w += r.w;
        }
    }
    __syncthreads();
    if (w == 2 || w == 3) {
#pragma unroll
        for (int a = 0; a < 8; a++) red4[w - 2][dg][a] = acc[a];
    }
    __syncthreads();
    if (w < 2) {
#pragma unroll
        for (int a = 0; a < 8; a++) {
            float4 r = red4[w][dg][a];
            acc[a].x += r.x; acc[a].y += r.y; acc[a].z += r.z; acc[a].w += r.w;
        }
    }
    __syncthreads();
    if (w == 1) {
#pragma unroll
        for (int a = 0; a < 8; a++) red4[0][dg][a] = acc[a];
    }
    __syncthreads();
    if (w == 0) {
#pragma unroll
        for (int a = 0; a < 8; a++) {
            float4 r = red4[0][dg][a];
            acc[a].x += r.x; acc[a].y += r.y; acc[a].z += r.z; acc[a].w += r.w;
            int n = nb + a;
            if (interleaved) {
                *(float4*)(out + ((size_t)n * D_PET + d0) * 2) = acc[a];
            } else {
                *(float2*)(out + (size_t)n * D_PET + d0) = make_float2(acc[a].x, acc[a].z);
            }
        }
    }
}

// ---------------------------------------------------------------------------
extern "C" void kernel_launch(void* const* d_in, const int* in_sizes, int n_in,
                              void* d_out, int out_size, void* d_ws, size_t ws_size,
                              hipStream_t stream) {
    const float* kvec = (const float*)d_in[0];
    const float* pos  = (const float*)d_in[1];
    const float* h    = (const float*)d_in[2];
    const float* W1   = (const float*)d_in[3];
    const float* b1   = (const float*)d_in[4];
    const float* W2   = (const float*)d_in[5];
    const float* b2   = (const float*)d_in[6];
    const float* W3   = (const float*)d_in[7];
    const float* b3   = (const float*)d_in[8];
    const int*   batch = (const int*)d_in[9];

    float* ws   = (float*)d_ws;
    float* filt = ws;                                    // 512K floats (2 MB)
    float* ts0  = filt + (size_t)NBATCH * NK * D_PET;    // 1M floats (4 MB)
    float* ts1  = ts0 + (size_t)NBATCH * NK * D_PET * 2; // 1M floats (4 MB)

    int interleaved = (out_size == NB * D_PET * 2) ? 1 : 0;

    smlp_kernel<<<1024, 256, 0, stream>>>(kvec, pos, h, batch,
                                          W1, b1, W2, b2, W3, b3, filt, ts0, ts1);
    out_kernel<<<256, 512, 0, stream>>>(kvec, pos, batch, ts0, ts1, filt,
                                        (float*)d_out, interleaved);
}

// Round 10
// 132.978 us; speedup vs baseline: 1.3414x; 1.3414x over previous
//
#include <hip/hip_runtime.h>
#include <math.h>

#define D_PET 128
#define NK    256
#define NB    2048
#define NBATCH 16

__device__ __forceinline__ float silu(float x) {
    return x / (1.0f + expf(-x));
}

__device__ __forceinline__ int lower_bound_dev(const int* a, int n, int v) {
    int lo = 0, hi = n;
    while (lo < hi) {
        int m = (lo + hi) >> 1;
        if (a[m] < v) lo = m + 1; else hi = m;
    }
    return lo;
}

// ---------------------------------------------------------------------------
// Kernel A (fused): blocks [0,1024) = s-partial blocks (b, 8-k tile, 2-way
// atom split; on-the-fly phases in LDS), blocks [1024,1536) = MLP -> filt.
// ---------------------------------------------------------------------------
#define S_BLOCKS 1024
#define MJ 8

// s atom-chunk: 4 atoms -> 4 h float4 loads + 4 LDS float2 reads -> 32 FMA
#define SLOAD(S, c0)                                                         \
    do {                                                                     \
        _Pragma("unroll")                                                    \
        for (int i_ = 0; i_ < 4; i_++) {                                     \
            int a_ = (c0) * 4 + i_;                                          \
            hb##S[i_] = *(const float4*)(hp + (size_t)(base + a_) * D_PET);  \
            cb##S[i_] = cs[a_ * 8 + kq];                                     \
        }                                                                    \
    } while (0)

#define SFMA(S)                                                              \
    do {                                                                     \
        _Pragma("unroll")                                                    \
        for (int i_ = 0; i_ < 4; i_++) {                                     \
            float4 hv = hb##S[i_]; float2 q = cb##S[i_];                     \
            re[0]=fmaf(q.x,hv.x,re[0]); im[0]=fmaf(-q.y,hv.x,im[0]);         \
            re[1]=fmaf(q.x,hv.y,re[1]); im[1]=fmaf(-q.y,hv.y,im[1]);         \
            re[2]=fmaf(q.x,hv.z,re[2]); im[2]=fmaf(-q.y,hv.z,im[2]);         \
            re[3]=fmaf(q.x,hv.w,re[3]); im[3]=fmaf(-q.y,hv.w,im[3]);         \
        }                                                                    \
    } while (0)

__global__ void __launch_bounds__(256) smlp_kernel(
                           const float* __restrict__ kvec,
                           const float* __restrict__ pos,
                           const float* __restrict__ h,
                           const int* __restrict__ batch,
                           const float* __restrict__ W1, const float* __restrict__ b1,
                           const float* __restrict__ W2, const float* __restrict__ b2,
                           const float* __restrict__ W3, const float* __restrict__ b3,
                           float* __restrict__ filt,
                           float* __restrict__ ts0,
                           float* __restrict__ ts1) {
    __shared__ float smem[24 + 2048];   // s: kv[8][3] + cs[128][8] f2 ; mlp: kv + x_lds

    if (blockIdx.x < S_BLOCKS) {
        // ---- s-partial: block = (b, kt of 8 k, sp atom half) ----
        int bi = blockIdx.x;
        int v  = (bi & 7) * 128 + (bi >> 3);  // XCD-contiguous, bijective (1024)
        int b  = v >> 6;
        int r  = v & 63;
        int kt = r >> 1;                      // 0..31
        int sp = r & 1;                       // atom half
        int dq = threadIdx.x & 31;
        int kq = threadIdx.x >> 5;            // 0..7
        int k  = kt * 8 + kq;
        int d0 = dq * 4;

        float*  kv_s = smem;                  // [8][3]
        float2* cs   = (float2*)(smem + 24);  // [128][8]

        if (threadIdx.x < 24)
            kv_s[threadIdx.x] = kvec[((size_t)b * NK + kt * 8) * 3 + threadIdx.x];

        int lo = lower_bound_dev(batch, NB, b);
        int hi = lower_bound_dev(batch, NB, b + 1);
        int cnt = hi - lo;
        int a0 = lo + ((cnt * sp) >> 1);
        int a1 = lo + ((cnt * (sp + 1)) >> 1);

        float re[4] = {0.f,0.f,0.f,0.f}, im[4] = {0.f,0.f,0.f,0.f};
        const float* hp = h + d0;

        for (int base = a0; base < a1; base += 128) {
            int m = a1 - base; if (m > 128) m = 128;
            __syncthreads();   // kv_s ready (1st iter) / prev chunk reads done
            // stage phases for this atom chunk: 4 (atom,k) pairs per thread
#pragma unroll
            for (int i = 0; i < 4; i++) {
                int p = threadIdx.x * 4 + i;
                int a = p >> 3, kk = p & 7;
                if (a < m) {
                    int n = base + a;
                    float ph = pos[n*3+0]*kv_s[kk*3+0]
                             + pos[n*3+1]*kv_s[kk*3+1]
                             + pos[n*3+2]*kv_s[kk*3+2];
                    float sv, cv; sincosf(ph, &sv, &cv);
                    cs[a * 8 + kk] = make_float2(cv, sv);
                }
            }
            __syncthreads();

            float4 hb0[4], hb1[4];
            float2 cb0[4], cb1[4];
            int nch = m >> 2;
            if (nch) {
                SLOAD(0, 0);
                int c = 1;
                for (; c + 1 < nch; c += 2) {
                    SLOAD(1, c);     __builtin_amdgcn_sched_barrier(0); SFMA(0);
                    SLOAD(0, c + 1); __builtin_amdgcn_sched_barrier(0); SFMA(1);
                }
                if (c < nch) {
                    SLOAD(1, c); __builtin_amdgcn_sched_barrier(0);
                    SFMA(0); SFMA(1);
                } else {
                    __builtin_amdgcn_sched_barrier(0); SFMA(0);
                }
            }
            for (int a = nch * 4; a < m; a++) {
                float4 hv = *(const float4*)(hp + (size_t)(base + a) * D_PET);
                float2 q  = cs[a * 8 + kq];
                re[0]=fmaf(q.x,hv.x,re[0]); im[0]=fmaf(-q.y,hv.x,im[0]);
                re[1]=fmaf(q.x,hv.y,re[1]); im[1]=fmaf(-q.y,hv.y,im[1]);
                re[2]=fmaf(q.x,hv.z,re[2]); im[2]=fmaf(-q.y,hv.z,im[2]);
                re[3]=fmaf(q.x,hv.w,re[3]); im[3]=fmaf(-q.y,hv.w,im[3]);
            }
        }

        float* dst = sp ? ts1 : ts0;
        size_t o = (((size_t)b * NK + k) * D_PET + d0) * 2;
        *(float4*)(dst + o)     = make_float4(re[0], im[0], re[1], im[1]);
        *(float4*)(dst + o + 4) = make_float4(re[2], im[2], re[3], im[3]);
        return;
    }

    // ---- MLP: filt[b,k,:] ----
    int bk0 = (blockIdx.x - S_BLOCKS) * MJ;
    int d   = threadIdx.x & (D_PET - 1);
    int jg  = threadIdx.x >> 7;

    float* kv_s  = smem;          // [MJ*3]
    float* x_lds = smem + 24;     // [D_PET*MJ]

    if (threadIdx.x < MJ * 3) kv_s[threadIdx.x] = kvec[bk0 * 3 + threadIdx.x];
    __syncthreads();

    float w10 = W1[0 * D_PET + d], w11 = W1[1 * D_PET + d], w12 = W1[2 * D_PET + d];
    float bb1 = b1[d];
    float4 x1;
    {
        float* xp = (float*)&x1;
#pragma unroll
        for (int i = 0; i < 4; i++) {
            int j = jg * 4 + i;
            float a = bb1;
            a = fmaf(kv_s[j * 3 + 0], w10, a);
            a = fmaf(kv_s[j * 3 + 1], w11, a);
            a = fmaf(kv_s[j * 3 + 2], w12, a);
            xp[i] = silu(a);
        }
    }
    *(float4*)&x_lds[(d << 3) + (jg << 2)] = x1;
    __syncthreads();

    float acc0 = b2[d], acc1 = acc0, acc2 = acc0, acc3 = acc0;
#pragma unroll
    for (int e0 = 0; e0 < D_PET; e0 += 8) {
        float w[8];
#pragma unroll
        for (int i = 0; i < 8; i++) w[i] = W2[(e0 + i) * D_PET + d];
        __builtin_amdgcn_sched_barrier(0);
#pragma unroll
        for (int i = 0; i < 8; i++) {
            float4 xv = *(const float4*)&x_lds[((e0 + i) << 3) + (jg << 2)];
            acc0 = fmaf(xv.x, w[i], acc0);
            acc1 = fmaf(xv.y, w[i], acc1);
            acc2 = fmaf(xv.z, w[i], acc2);
            acc3 = fmaf(xv.w, w[i], acc3);
        }
    }
    float4 x2 = make_float4(silu(acc0), silu(acc1), silu(acc2), silu(acc3));
    __syncthreads();
    *(float4*)&x_lds[(d << 3) + (jg << 2)] = x2;
    __syncthreads();

    float o0 = b3[d], o1 = o0, o2 = o0, o3 = o0;
#pragma unroll
    for (int e0 = 0; e0 < D_PET; e0 += 8) {
        float w[8];
#pragma unroll
        for (int i = 0; i < 8; i++) w[i] = W3[(e0 + i) * D_PET + d];
        __builtin_amdgcn_sched_barrier(0);
#pragma unroll
        for (int i = 0; i < 8; i++) {
            float4 xv = *(const float4*)&x_lds[((e0 + i) << 3) + (jg << 2)];
            o0 = fmaf(xv.x, w[i], o0);
            o1 = fmaf(xv.y, w[i], o1);
            o2 = fmaf(xv.z, w[i], o2);
            o3 = fmaf(xv.w, w[i], o3);
        }
    }
    float out4[4] = {o0, o1, o2, o3};
#pragma unroll
    for (int i = 0; i < 4; i++) {
        int j = jg * 4 + i;
        filt[(size_t)(bk0 + j) * D_PET + d] = out4[i];
    }
}

// ---------------------------------------------------------------------------
// Kernel B (round-8 v8 structure; t = ts0+ts1 combined on the fly):
// out[n,d] = sum_k e^{+i phi_nk} * (ts0+ts1)[b,k,d]*filt[b,k,d]
// grid = 512 blocks x 512 threads. Block = 4 atoms x 128 d, k quartered
// across wave-groups. Thread = 2 atoms x 2 d x 64 k. Phases in LDS.
// bA==bB (common): ONE t/f stream feeds both atoms. 2-set pipeline.
// 4-way LDS reduce over k-quarters.
// ---------------------------------------------------------------------------
#define OLOADU(S, c)                                                         \
    do {                                                                     \
        _Pragma("unroll")                                                    \
        for (int j_ = 0; j_ < 2; j_++) {                                     \
            int k_ = k0 + (c) * 2 + j_;                                      \
            t0_##S[j_] = *(const float4*)(tb0 + (size_t)k_ * (2 * D_PET));   \
            t1_##S[j_] = *(const float4*)(tb1 + (size_t)k_ * (2 * D_PET));   \
            f_##S[j_]  = *(const float2*)(fb  + (size_t)k_ * D_PET);         \
            qA_##S[j_] = csA[k_]; qB_##S[j_] = csB[k_];                      \
        }                                                                    \
    } while (0)

#define OFMAU(S)                                                             \
    do {                                                                     \
        _Pragma("unroll")                                                    \
        for (int j_ = 0; j_ < 2; j_++) {                                     \
            float4 u0 = t0_##S[j_], u1 = t1_##S[j_];                         \
            float2 f = f_##S[j_];                                            \
            float tr0 = (u0.x + u1.x) * f.x, ti0 = (u0.y + u1.y) * f.x;      \
            float tr1 = (u0.z + u1.z) * f.y, ti1 = (u0.w + u1.w) * f.y;      \
            float2 q = qA_##S[j_];                                           \
            aAr0 = fmaf(q.x,tr0,aAr0); aAr0 = fmaf(-q.y,ti0,aAr0);           \
            aAi0 = fmaf(q.x,ti0,aAi0); aAi0 = fmaf( q.y,tr0,aAi0);           \
            aAr1 = fmaf(q.x,tr1,aAr1); aAr1 = fmaf(-q.y,ti1,aAr1);           \
            aAi1 = fmaf(q.x,ti1,aAi1); aAi1 = fmaf( q.y,tr1,aAi1);           \
            q = qB_##S[j_];                                                  \
            aBr0 = fmaf(q.x,tr0,aBr0); aBr0 = fmaf(-q.y,ti0,aBr0);           \
            aBi0 = fmaf(q.x,ti0,aBi0); aBi0 = fmaf( q.y,tr0,aBi0);           \
            aBr1 = fmaf(q.x,tr1,aBr1); aBr1 = fmaf(-q.y,ti1,aBr1);           \
            aBi1 = fmaf(q.x,ti1,aBi1); aBi1 = fmaf( q.y,tr1,aBi1);           \
        }                                                                    \
    } while (0)

__global__ void __launch_bounds__(512) out_kernel(
                           const float* __restrict__ kvec,
                           const float* __restrict__ pos,
                           const int* __restrict__ batch,
                           const float* __restrict__ ts0,
                           const float* __restrict__ ts1,
                           const float* __restrict__ filt,
                           float* __restrict__ out, int interleaved) {
    __shared__ float2 cs[4 * 256];          // 8 KB phases
    __shared__ float  red[3][2][64][8];     // 12 KB k-quarter reduce

    int bi = blockIdx.x;
    int v  = (bi & 7) * 64 + (bi >> 3);     // XCD-contiguous: 2 batches/XCD
    int nb = v * 4;
    int dg = threadIdx.x & 63;
    int w  = threadIdx.x >> 6;              // 0..7
    int ng = w & 1;                         // atom pair
    int kh = w >> 1;                        // k quarter
    int d0 = dg * 2;
    int k0 = kh * 64;

    // stage phases: 2 (atom,k) pairs per thread
#pragma unroll
    for (int i = 0; i < 2; i++) {
        int p = threadIdx.x * 2 + i;
        int a = p >> 8, k = p & 255;
        int n = nb + a;
        int b = batch[n];
        const float* kv = kvec + ((size_t)b * NK + k) * 3;
        float ph = pos[n*3+0]*kv[0] + pos[n*3+1]*kv[1] + pos[n*3+2]*kv[2];
        float sv, cv; sincosf(ph, &sv, &cv);
        cs[a * 256 + k] = make_float2(cv, sv);
    }
    __syncthreads();

    int nA = nb + ng * 2, nB = nA + 1;
    int bA = batch[nA], bB = batch[nB];
    const float2* csA = cs + (ng * 2) * 256;
    const float2* csB = csA + 256;

    float aAr0=0.f, aAi0=0.f, aAr1=0.f, aAi1=0.f;
    float aBr0=0.f, aBi0=0.f, aBr1=0.f, aBi1=0.f;

    if (bA == bB) {
        const float* tb0 = ts0  + ((size_t)bA * NK * D_PET + d0) * 2;
        const float* tb1 = ts1  + ((size_t)bA * NK * D_PET + d0) * 2;
        const float* fb  = filt +  (size_t)bA * NK * D_PET + d0;

        float4 t0_0[2], t0_1[2], t1_0[2], t1_1[2];
        float2 f_0[2], f_1[2];
        float2 qA_0[2], qA_1[2], qB_0[2], qB_1[2];

        OLOADU(0, 0);
#pragma unroll
        for (int c = 1; c + 1 < 32; c += 2) {
            OLOADU(1, c);     __builtin_amdgcn_sched_barrier(0); OFMAU(0);
            OLOADU(0, c + 1); __builtin_amdgcn_sched_barrier(0); OFMAU(1);
        }
        OLOADU(1, 31); __builtin_amdgcn_sched_barrier(0); OFMAU(0); OFMAU(1);
    } else {
        // batch boundary inside the atom pair (rare, wave-uniform)
        const float* tA0 = ts0  + ((size_t)bA * NK * D_PET + d0) * 2;
        const float* tA1 = ts1  + ((size_t)bA * NK * D_PET + d0) * 2;
        const float* fA  = filt +  (size_t)bA * NK * D_PET + d0;
        const float* tB0 = ts0  + ((size_t)bB * NK * D_PET + d0) * 2;
        const float* tB1 = ts1  + ((size_t)bB * NK * D_PET + d0) * 2;
        const float* fB  = filt +  (size_t)bB * NK * D_PET + d0;
        for (int k = k0; k < k0 + 64; k++) {
            float4 uA0 = *(const float4*)(tA0 + (size_t)k * (2 * D_PET));
            float4 uA1 = *(const float4*)(tA1 + (size_t)k * (2 * D_PET));
            float2 fa  = *(const float2*)(fA  + (size_t)k * D_PET);
            float4 uB0 = *(const float4*)(tB0 + (size_t)k * (2 * D_PET));
            float4 uB1 = *(const float4*)(tB1 + (size_t)k * (2 * D_PET));
            float2 fb2 = *(const float2*)(fB  + (size_t)k * D_PET);
            float2 qa = csA[k], qb = csB[k];
            float tr0 = (uA0.x + uA1.x) * fa.x, ti0 = (uA0.y + uA1.y) * fa.x;
            float tr1 = (uA0.z + uA1.z) * fa.y, ti1 = (uA0.w + uA1.w) * fa.y;
            aAr0 = fmaf(qa.x,tr0,aAr0); aAr0 = fmaf(-qa.y,ti0,aAr0);
            aAi0 = fmaf(qa.x,ti0,aAi0); aAi0 = fmaf( qa.y,tr0,aAi0);
            aAr1 = fmaf(qa.x,tr1,aAr1); aAr1 = fmaf(-qa.y,ti1,aAr1);
            aAi1 = fmaf(qa.x,ti1,aAi1); aAi1 = fmaf( qa.y,tr1,aAi1);
            tr0 = (uB0.x + uB1.x) * fb2.x; ti0 = (uB0.y + uB1.y) * fb2.x;
            tr1 = (uB0.z + uB1.z) * fb2.y; ti1 = (uB0.w + uB1.w) * fb2.y;
            aBr0 = fmaf(qb.x,tr0,aBr0); aBr0 = fmaf(-qb.y,ti0,aBr0);
            aBi0 = fmaf(qb.x,ti0,aBi0); aBi0 = fmaf( qb.y,tr0,aBi0);
            aBr1 = fmaf(qb.x,tr1,aBr1); aBr1 = fmaf(-qb.y,ti1,aBr1);
            aBi1 = fmaf(qb.x,ti1,aBi1); aBi1 = fmaf( qb.y,tr1,aBi1);
        }
    }

    // combine k-quarters
    if (kh > 0) {
        float* r = red[kh - 1][ng][dg];
        *(float4*)&r[0] = make_float4(aAr0, aAi0, aAr1, aAi1);
        *(float4*)&r[4] = make_float4(aBr0, aBi0, aBr1, aBi1);
    }
    __syncthreads();
    if (kh == 0) {
#pragma unroll
        for (int q_ = 0; q_ < 3; q_++) {
            const float* r = red[q_][ng][dg];
            aAr0 += r[0]; aAi0 += r[1]; aAr1 += r[2]; aAi1 += r[3];
            aBr0 += r[4]; aBi0 += r[5]; aBr1 += r[6]; aBi1 += r[7];
        }
        if (interleaved) {
            *(float4*)(out + ((size_t)nA * D_PET + d0) * 2) = make_float4(aAr0, aAi0, aAr1, aAi1);
            *(float4*)(out + ((size_t)nB * D_PET + d0) * 2) = make_float4(aBr0, aBi0, aBr1, aBi1);
        } else {
            *(float2*)(out + (size_t)nA * D_PET + d0) = make_float2(aAr0, aAr1);
            *(float2*)(out + (size_t)nB * D_PET + d0) = make_float2(aBr0, aBr1);
        }
    }
}

// ---------------------------------------------------------------------------
extern "C" void kernel_launch(void* const* d_in, const int* in_sizes, int n_in,
                              void* d_out, int out_size, void* d_ws, size_t ws_size,
                              hipStream_t stream) {
    const float* kvec = (const float*)d_in[0];
    const float* pos  = (const float*)d_in[1];
    const float* h    = (const float*)d_in[2];
    const float* W1   = (const float*)d_in[3];
    const float* b1   = (const float*)d_in[4];
    const float* W2   = (const float*)d_in[5];
    const float* b2   = (const float*)d_in[6];
    const float* W3   = (const float*)d_in[7];
    const float* b3   = (const float*)d_in[8];
    const int*   batch = (const int*)d_in[9];

    float* ws   = (float*)d_ws;
    float* filt = ws;                                    // 512K floats (2 MB)
    float* ts0  = filt + (size_t)NBATCH * NK * D_PET;    // 1M floats (4 MB)
    float* ts1  = ts0 + (size_t)NBATCH * NK * D_PET * 2; // 1M floats (4 MB)

    int interleaved = (out_size == NB * D_PET * 2) ? 1 : 0;

    smlp_kernel<<<S_BLOCKS + NBATCH * NK / MJ, 256, 0, stream>>>(
        kvec, pos, h, batch, W1, b1, W2, b2, W3, b3, filt, ts0, ts1);
    out_kernel<<<512, 512, 0, stream>>>(kvec, pos, batch, ts0, ts1, filt,
                                        (float*)d_out, interleaved);
}

// Round 11
// 119.928 us; speedup vs baseline: 1.4873x; 1.1088x over previous
//
#include <hip/hip_runtime.h>
#include <math.h>

#define D_PET 128
#define NK    256
#define NB    2048
#define NBATCH 16

__device__ __forceinline__ float silu(float x) {
    return x / (1.0f + expf(-x));
}

__device__ __forceinline__ int lower_bound_dev(const int* a, int n, int v) {
    int lo = 0, hi = n;
    while (lo < hi) {
        int m = (lo + hi) >> 1;
        if (a[m] < v) lo = m + 1; else hi = m;
    }
    return lo;
}

// ---------------------------------------------------------------------------
// Kernel A (fused): blocks [0,512) = s-partial blocks (on-the-fly phases via
// LDS staging, write ts WITHOUT filt), blocks [512,1024) = MLP -> filt.
// ---------------------------------------------------------------------------
#define S_BLOCKS 512
#define MJ 8

// s atom-chunk: 4 atoms -> 4 h float4 loads + 4 LDS float2 reads -> 32 FMA
#define SLOAD(S, c0)                                                         \
    do {                                                                     \
        _Pragma("unroll")                                                    \
        for (int i_ = 0; i_ < 4; i_++) {                                     \
            int a_ = (c0) * 4 + i_;                                          \
            hb##S[i_] = *(const float4*)(hp + (size_t)(base + a_) * D_PET);  \
            cb##S[i_] = cs[a_ * 8 + kq];                                     \
        }                                                                    \
    } while (0)

#define SFMA(S)                                                              \
    do {                                                                     \
        _Pragma("unroll")                                                    \
        for (int i_ = 0; i_ < 4; i_++) {                                     \
            float4 hv = hb##S[i_]; float2 q = cb##S[i_];                     \
            re[0]=fmaf(q.x,hv.x,re[0]); im[0]=fmaf(-q.y,hv.x,im[0]);         \
            re[1]=fmaf(q.x,hv.y,re[1]); im[1]=fmaf(-q.y,hv.y,im[1]);         \
            re[2]=fmaf(q.x,hv.z,re[2]); im[2]=fmaf(-q.y,hv.z,im[2]);         \
            re[3]=fmaf(q.x,hv.w,re[3]); im[3]=fmaf(-q.y,hv.w,im[3]);         \
        }                                                                    \
    } while (0)

__global__ void __launch_bounds__(256) smlp_kernel(
                           const float* __restrict__ kvec,
                           const float* __restrict__ pos,
                           const float* __restrict__ h,
                           const int* __restrict__ batch,
                           const float* __restrict__ W1, const float* __restrict__ b1,
                           const float* __restrict__ W2, const float* __restrict__ b2,
                           const float* __restrict__ W3, const float* __restrict__ b3,
                           float* __restrict__ filt,
                           float* __restrict__ ts) {
    __shared__ float smem[24 + 2048];   // s: kv[8][3] + cs[128][8] f2 ; mlp: kv + x_lds

    if (blockIdx.x < S_BLOCKS) {
        // ---- s-partial: block = (b, kt of 8 k) ----
        int bi = blockIdx.x;
        int v  = (bi & 7) * 64 + (bi >> 3);   // XCD-contiguous: 2 batches/XCD
        int b  = v >> 5;
        int kt = v & 31;
        int dq = threadIdx.x & 31;
        int kq = threadIdx.x >> 5;            // 0..7
        int k  = kt * 8 + kq;
        int d0 = dq * 4;

        float*  kv_s = smem;                  // [8][3]
        float2* cs   = (float2*)(smem + 24);  // [128][8]

        if (threadIdx.x < 24)
            kv_s[threadIdx.x] = kvec[((size_t)b * NK + kt * 8) * 3 + threadIdx.x];

        int lo = lower_bound_dev(batch, NB, b);
        int hi = lower_bound_dev(batch, NB, b + 1);

        float re[4] = {0.f,0.f,0.f,0.f}, im[4] = {0.f,0.f,0.f,0.f};
        const float* hp = h + d0;

        for (int base = lo; base < hi; base += 128) {
            int m = hi - base; if (m > 128) m = 128;
            __syncthreads();   // kv_s ready (1st iter) / prev chunk reads done
            // stage phases for this atom chunk: 4 (atom,k) pairs per thread
#pragma unroll
            for (int i = 0; i < 4; i++) {
                int p = threadIdx.x * 4 + i;
                int a = p >> 3, kk = p & 7;
                if (a < m) {
                    int n = base + a;
                    float ph = pos[n*3+0]*kv_s[kk*3+0]
                             + pos[n*3+1]*kv_s[kk*3+1]
                             + pos[n*3+2]*kv_s[kk*3+2];
                    float sv, cv; sincosf(ph, &sv, &cv);
                    cs[a * 8 + kk] = make_float2(cv, sv);
                }
            }
            __syncthreads();

            float4 hb0[4], hb1[4];
            float2 cb0[4], cb1[4];
            int nch = m >> 2;
            if (nch) {
                SLOAD(0, 0);
                int c = 1;
                for (; c + 1 < nch; c += 2) {
                    SLOAD(1, c);     __builtin_amdgcn_sched_barrier(0); SFMA(0);
                    SLOAD(0, c + 1); __builtin_amdgcn_sched_barrier(0); SFMA(1);
                }
                if (c < nch) {
                    SLOAD(1, c); __builtin_amdgcn_sched_barrier(0);
                    SFMA(0); SFMA(1);
                } else {
                    __builtin_amdgcn_sched_barrier(0); SFMA(0);
                }
            }
            for (int a = nch * 4; a < m; a++) {
                float4 hv = *(const float4*)(hp + (size_t)(base + a) * D_PET);
                float2 q  = cs[a * 8 + kq];
                re[0]=fmaf(q.x,hv.x,re[0]); im[0]=fmaf(-q.y,hv.x,im[0]);
                re[1]=fmaf(q.x,hv.y,re[1]); im[1]=fmaf(-q.y,hv.y,im[1]);
                re[2]=fmaf(q.x,hv.z,re[2]); im[2]=fmaf(-q.y,hv.z,im[2]);
                re[3]=fmaf(q.x,hv.w,re[3]); im[3]=fmaf(-q.y,hv.w,im[3]);
            }
        }

        size_t o = (((size_t)b * NK + k) * D_PET + d0) * 2;
        *(float4*)(ts + o)     = make_float4(re[0], im[0], re[1], im[1]);
        *(float4*)(ts + o + 4) = make_float4(re[2], im[2], re[3], im[3]);
        return;
    }

    // ---- MLP: filt[b,k,:] ----
    int bk0 = (blockIdx.x - S_BLOCKS) * MJ;
    int d   = threadIdx.x & (D_PET - 1);
    int jg  = threadIdx.x >> 7;

    float* kv_s  = smem;          // [MJ*3]
    float* x_lds = smem + 24;     // [D_PET*MJ]

    if (threadIdx.x < MJ * 3) kv_s[threadIdx.x] = kvec[bk0 * 3 + threadIdx.x];
    __syncthreads();

    float w10 = W1[0 * D_PET + d], w11 = W1[1 * D_PET + d], w12 = W1[2 * D_PET + d];
    float bb1 = b1[d];
    float4 x1;
    {
        float* xp = (float*)&x1;
#pragma unroll
        for (int i = 0; i < 4; i++) {
            int j = jg * 4 + i;
            float a = bb1;
            a = fmaf(kv_s[j * 3 + 0], w10, a);
            a = fmaf(kv_s[j * 3 + 1], w11, a);
            a = fmaf(kv_s[j * 3 + 2], w12, a);
            xp[i] = silu(a);
        }
    }
    *(float4*)&x_lds[(d << 3) + (jg << 2)] = x1;
    __syncthreads();

    float acc0 = b2[d], acc1 = acc0, acc2 = acc0, acc3 = acc0;
#pragma unroll
    for (int e0 = 0; e0 < D_PET; e0 += 8) {
        float w[8];
#pragma unroll
        for (int i = 0; i < 8; i++) w[i] = W2[(e0 + i) * D_PET + d];
        __builtin_amdgcn_sched_barrier(0);
#pragma unroll
        for (int i = 0; i < 8; i++) {
            float4 xv = *(const float4*)&x_lds[((e0 + i) << 3) + (jg << 2)];
            acc0 = fmaf(xv.x, w[i], acc0);
            acc1 = fmaf(xv.y, w[i], acc1);
            acc2 = fmaf(xv.z, w[i], acc2);
            acc3 = fmaf(xv.w, w[i], acc3);
        }
    }
    float4 x2 = make_float4(silu(acc0), silu(acc1), silu(acc2), silu(acc3));
    __syncthreads();
    *(float4*)&x_lds[(d << 3) + (jg << 2)] = x2;
    __syncthreads();

    float o0 = b3[d], o1 = o0, o2 = o0, o3 = o0;
#pragma unroll
    for (int e0 = 0; e0 < D_PET; e0 += 8) {
        float w[8];
#pragma unroll
        for (int i = 0; i < 8; i++) w[i] = W3[(e0 + i) * D_PET + d];
        __builtin_amdgcn_sched_barrier(0);
#pragma unroll
        for (int i = 0; i < 8; i++) {
            float4 xv = *(const float4*)&x_lds[((e0 + i) << 3) + (jg << 2)];
            o0 = fmaf(xv.x, w[i], o0);
            o1 = fmaf(xv.y, w[i], o1);
            o2 = fmaf(xv.z, w[i], o2);
            o3 = fmaf(xv.w, w[i], o3);
        }
    }
    float out4[4] = {o0, o1, o2, o3};
#pragma unroll
    for (int i = 0; i < 4; i++) {
        int j = jg * 4 + i;
        filt[(size_t)(bk0 + j) * D_PET + d] = out4[i];
    }
}

// ---------------------------------------------------------------------------
// Kernel B (v8 = round-6 structure + t/filt CSE for the uniform atom pair):
// out[n,d] = sum_k e^{+i phi_nk} * ts[b,k,d]*filt[b,k,d]
// grid = 512 blocks x 512 threads. Block = 4 atoms x 128 d, k quartered
// across wave-groups. Thread = 2 atoms x 2 d x 64 k. Phases in LDS.
// bA==bB (common): ONE t/f stream feeds both atoms -> 4 global loads +
// 4 LDS f2 per 2k-chunk, 2-set pipeline. 4-way LDS reduce over k-quarters.
// ---------------------------------------------------------------------------
#define OLOADU(S, c)                                                         \
    do {                                                                     \
        _Pragma("unroll")                                                    \
        for (int j_ = 0; j_ < 2; j_++) {                                     \
            int k_ = k0 + (c) * 2 + j_;                                      \
            t_##S[j_] = *(const float4*)(tb + (size_t)k_ * (2 * D_PET));     \
            f_##S[j_] = *(const float2*)(fb + (size_t)k_ * D_PET);           \
            qA_##S[j_] = csA[k_]; qB_##S[j_] = csB[k_];                      \
        }                                                                    \
    } while (0)

#define OFMAU(S)                                                             \
    do {                                                                     \
        _Pragma("unroll")                                                    \
        for (int j_ = 0; j_ < 2; j_++) {                                     \
            float4 u = t_##S[j_]; float2 f = f_##S[j_];                      \
            float tr0 = u.x*f.x, ti0 = u.y*f.x, tr1 = u.z*f.y, ti1 = u.w*f.y;\
            float2 q = qA_##S[j_];                                           \
            aAr0 = fmaf(q.x,tr0,aAr0); aAr0 = fmaf(-q.y,ti0,aAr0);           \
            aAi0 = fmaf(q.x,ti0,aAi0); aAi0 = fmaf( q.y,tr0,aAi0);           \
            aAr1 = fmaf(q.x,tr1,aAr1); aAr1 = fmaf(-q.y,ti1,aAr1);           \
            aAi1 = fmaf(q.x,ti1,aAi1); aAi1 = fmaf( q.y,tr1,aAi1);           \
            q = qB_##S[j_];                                                  \
            aBr0 = fmaf(q.x,tr0,aBr0); aBr0 = fmaf(-q.y,ti0,aBr0);           \
            aBi0 = fmaf(q.x,ti0,aBi0); aBi0 = fmaf( q.y,tr0,aBi0);           \
            aBr1 = fmaf(q.x,tr1,aBr1); aBr1 = fmaf(-q.y,ti1,aBr1);           \
            aBi1 = fmaf(q.x,ti1,aBi1); aBi1 = fmaf( q.y,tr1,aBi1);           \
        }                                                                    \
    } while (0)

__global__ void __launch_bounds__(512) out_kernel(
                           const float* __restrict__ kvec,
                           const float* __restrict__ pos,
                           const int* __restrict__ batch,
                           const float* __restrict__ ts,
                           const float* __restrict__ filt,
                           float* __restrict__ out, int interleaved) {
    __shared__ float2 cs[4 * 256];          // 8 KB phases
    __shared__ float  red[3][2][64][8];     // 12 KB k-quarter reduce

    int bi = blockIdx.x;
    int v  = (bi & 7) * 64 + (bi >> 3);     // XCD-contiguous: 2 batches/XCD
    int nb = v * 4;
    int dg = threadIdx.x & 63;
    int w  = threadIdx.x >> 6;              // 0..7
    int ng = w & 1;                         // atom pair
    int kh = w >> 1;                        // k quarter
    int d0 = dg * 2;
    int k0 = kh * 64;

    // stage phases: 2 (atom,k) pairs per thread
#pragma unroll
    for (int i = 0; i < 2; i++) {
        int p = threadIdx.x * 2 + i;
        int a = p >> 8, k = p & 255;
        int n = nb + a;
        int b = batch[n];
        const float* kv = kvec + ((size_t)b * NK + k) * 3;
        float ph = pos[n*3+0]*kv[0] + pos[n*3+1]*kv[1] + pos[n*3+2]*kv[2];
        float sv, cv; sincosf(ph, &sv, &cv);
        cs[a * 256 + k] = make_float2(cv, sv);
    }
    __syncthreads();

    int nA = nb + ng * 2, nB = nA + 1;
    int bA = batch[nA], bB = batch[nB];
    const float2* csA = cs + (ng * 2) * 256;
    const float2* csB = csA + 256;

    float aAr0=0.f, aAi0=0.f, aAr1=0.f, aAi1=0.f;
    float aBr0=0.f, aBi0=0.f, aBr1=0.f, aBi1=0.f;

    if (bA == bB) {
        const float* tb = ts   + ((size_t)bA * NK * D_PET + d0) * 2;
        const float* fb = filt +  (size_t)bA * NK * D_PET + d0;

        float4 t_0[2], t_1[2];
        float2 f_0[2], f_1[2];
        float2 qA_0[2], qA_1[2], qB_0[2], qB_1[2];

        OLOADU(0, 0);
#pragma unroll
        for (int c = 1; c + 1 < 32; c += 2) {
            OLOADU(1, c);     __builtin_amdgcn_sched_barrier(0); OFMAU(0);
            OLOADU(0, c + 1); __builtin_amdgcn_sched_barrier(0); OFMAU(1);
        }
        OLOADU(1, 31); __builtin_amdgcn_sched_barrier(0); OFMAU(0); OFMAU(1);
    } else {
        // batch boundary inside the atom pair (rare, wave-uniform)
        const float* tA = ts   + ((size_t)bA * NK * D_PET + d0) * 2;
        const float* fA = filt +  (size_t)bA * NK * D_PET + d0;
        const float* tB = ts   + ((size_t)bB * NK * D_PET + d0) * 2;
        const float* fB = filt +  (size_t)bB * NK * D_PET + d0;
        for (int k = k0; k < k0 + 64; k++) {
            float4 uA = *(const float4*)(tA + (size_t)k * (2 * D_PET));
            float2 fa = *(const float2*)(fA + (size_t)k * D_PET);
            float4 uB = *(const float4*)(tB + (size_t)k * (2 * D_PET));
            float2 fb2 = *(const float2*)(fB + (size_t)k * D_PET);
            float2 qa = csA[k], qb = csB[k];
            float tr0 = uA.x*fa.x, ti0 = uA.y*fa.x, tr1 = uA.z*fa.y, ti1 = uA.w*fa.y;
            aAr0 = fmaf(qa.x,tr0,aAr0); aAr0 = fmaf(-qa.y,ti0,aAr0);
            aAi0 = fmaf(qa.x,ti0,aAi0); aAi0 = fmaf( qa.y,tr0,aAi0);
            aAr1 = fmaf(qa.x,tr1,aAr1); aAr1 = fmaf(-qa.y,ti1,aAr1);
            aAi1 = fmaf(qa.x,ti1,aAi1); aAi1 = fmaf( qa.y,tr1,aAi1);
            tr0 = uB.x*fb2.x; ti0 = uB.y*fb2.x; tr1 = uB.z*fb2.y; ti1 = uB.w*fb2.y;
            aBr0 = fmaf(qb.x,tr0,aBr0); aBr0 = fmaf(-qb.y,ti0,aBr0);
            aBi0 = fmaf(qb.x,ti0,aBi0); aBi0 = fmaf( qb.y,tr0,aBi0);
            aBr1 = fmaf(qb.x,tr1,aBr1); aBr1 = fmaf(-qb.y,ti1,aBr1);
            aBi1 = fmaf(qb.x,ti1,aBi1); aBi1 = fmaf( qb.y,tr1,aBi1);
        }
    }

    // combine k-quarters
    if (kh > 0) {
        float* r = red[kh - 1][ng][dg];
        *(float4*)&r[0] = make_float4(aAr0, aAi0, aAr1, aAi1);
        *(float4*)&r[4] = make_float4(aBr0, aBi0, aBr1, aBi1);
    }
    __syncthreads();
    if (kh == 0) {
#pragma unroll
        for (int q_ = 0; q_ < 3; q_++) {
            const float* r = red[q_][ng][dg];
            aAr0 += r[0]; aAi0 += r[1]; aAr1 += r[2]; aAi1 += r[3];
            aBr0 += r[4]; aBi0 += r[5]; aBr1 += r[6]; aBi1 += r[7];
        }
        if (interleaved) {
            *(float4*)(out + ((size_t)nA * D_PET + d0) * 2) = make_float4(aAr0, aAi0, aAr1, aAi1);
            *(float4*)(out + ((size_t)nB * D_PET + d0) * 2) = make_float4(aBr0, aBi0, aBr1, aBi1);
        } else {
            *(float2*)(out + (size_t)nA * D_PET + d0) = make_float2(aAr0, aAr1);
            *(float2*)(out + (size_t)nB * D_PET + d0) = make_float2(aBr0, aBr1);
        }
    }
}

// ---------------------------------------------------------------------------
extern "C" void kernel_launch(void* const* d_in, const int* in_sizes, int n_in,
                              void* d_out, int out_size, void* d_ws, size_t ws_size,
                              hipStream_t stream) {
    const float* kvec = (const float*)d_in[0];
    const float* pos  = (const float*)d_in[1];
    const float* h    = (const float*)d_in[2];
    const float* W1   = (const float*)d_in[3];
    const float* b1   = (const float*)d_in[4];
    const float* W2   = (const float*)d_in[5];
    const float* b2   = (const float*)d_in[6];
    const float* W3   = (const float*)d_in[7];
    const float* b3   = (const float*)d_in[8];
    const int*   batch = (const int*)d_in[9];

    float* ws   = (float*)d_ws;
    float* filt = ws;                                    // 512K floats (2 MB)
    float* ts   = filt + (size_t)NBATCH * NK * D_PET;    // 1M floats (4 MB)

    int interleaved = (out_size == NB * D_PET * 2) ? 1 : 0;

    smlp_kernel<<<1024, 256, 0, stream>>>(kvec, pos, h, batch,
                                          W1, b1, W2, b2, W3, b3, filt, ts);
    out_kernel<<<512, 512, 0, stream>>>(kvec, pos, batch, ts, filt,
                                        (float*)d_out, interleaved);
}